// Round 12
// baseline (253.374 us; speedup 1.0000x reference)
//
#include <hip/hip_runtime.h>
#include <math.h>

// ---------------- types / helpers ----------------
typedef short s16x8 __attribute__((ext_vector_type(8)));     // 8 bf16 in 4 VGPRs
typedef unsigned short u16;
typedef unsigned short u16x4 __attribute__((ext_vector_type(4)));
typedef float f32x4 __attribute__((ext_vector_type(4)));

__device__ __forceinline__ f32x4 mfma16(s16x8 a, s16x8 b, f32x4 c) {
  return __builtin_amdgcn_mfma_f32_16x16x32_bf16(a, b, c, 0, 0, 0);
}

// fp32 -> bf16 bits, round-to-nearest-even
__device__ __forceinline__ u16 f2bf(float f) {
  unsigned u = __builtin_bit_cast(unsigned, f);
  u = (u + 0x7fffu + ((u >> 16) & 1u)) >> 16;
  return (u16)u;
}

// pack two fp32 -> two truncated bf16 in one v_perm
__device__ __forceinline__ unsigned pk_trunc(float hi, float lo) {
  return __builtin_amdgcn_perm(__builtin_bit_cast(unsigned, hi),
                               __builtin_bit_cast(unsigned, lo), 0x07060302u);
}

__device__ __forceinline__ s16x8 mk_pa(unsigned a, unsigned b, unsigned c, unsigned d) {
  union { unsigned u[4]; s16x8 h; } t;
  t.u[0] = a; t.u[1] = b; t.u[2] = c; t.u[3] = d;
  return t.h;
}

// async global->LDS, 16B per lane; lds base wave-uniform, lane i lands at base + i*16
__device__ __forceinline__ void gll16(const void* g, void* l) {
  __builtin_amdgcn_global_load_lds((__attribute__((address_space(1))) void*)(void*)g,
                                   (__attribute__((address_space(3))) void*)l,
                                   16, 0, 0);
}

// ---------------- fused prep: x->bf16 convert + both weight transposes ----------------
// R9 LESSON: do NOT fuse the x-convert into gemm0 via fp32 LDS staging. fp32 A-tile
// row stride = 128B makes the fragment-read bank index independent of r -> 16-way
// conflict (SQ_LDS_BANK_CONFLICT 6.29M -> 22.0M, gemm0 72 -> 110.6 us). The bf16
// 64B-stride layout is at the balanced 8-accesses/bank floor. Convert stays here.
__device__ __forceinline__ void transpose_body(const float* __restrict__ in,
                                               u16* __restrict__ out, int R, int C,
                                               int bx, int by, float (*tile)[33]) {
  int c0 = bx * 32, r0 = by * 32;
  int tx = threadIdx.x & 31, ty = threadIdx.x >> 5;  // 32 x 8
#pragma unroll
  for (int s = 0; s < 4; ++s)
    tile[ty + 8 * s][tx] = in[(size_t)(r0 + ty + 8 * s) * C + c0 + tx];
  __syncthreads();
#pragma unroll
  for (int s = 0; s < 4; ++s)
    out[(size_t)(c0 + ty + 8 * s) * R + r0 + tx] = f2bf(tile[tx][ty + 8 * s]);
}

__global__ __launch_bounds__(256) void k_prep(const float* __restrict__ x,
                                              u16* __restrict__ xb,
                                              const float* __restrict__ w_attn,
                                              u16* __restrict__ waT,
                                              const float* __restrict__ w_proj,
                                              u16* __restrict__ wpT) {
  __shared__ float tile[32][33];
  int id = blockIdx.x;
  if (id < 4096) {
    int i = (id * 256 + threadIdx.x) * 8;
    const float4* xv = (const float4*)(x + i);
    float4 a = xv[0], b = xv[1];
    union { s16x8 v; u16 s[8]; } r;
    r.s[0] = f2bf(a.x); r.s[1] = f2bf(a.y); r.s[2] = f2bf(a.z); r.s[3] = f2bf(a.w);
    r.s[4] = f2bf(b.x); r.s[5] = f2bf(b.y); r.s[6] = f2bf(b.z); r.s[7] = f2bf(b.w);
    *(s16x8*)(xb + i) = r.v;
  } else if (id < 4096 + 3072) {
    int t = id - 4096;                      // w_attn [1024][3072] -> [3072][1024]
    transpose_body(w_attn, waT, 1024, 3072, t % 96, t / 96, tile);
  } else {
    int t = id - (4096 + 3072);             // w_proj [1024][1024] -> [1024][1024]^T
    transpose_body(w_proj, wpT, 1024, 1024, t % 32, t / 32, tile);
  }
}

// ---------------- GEMM0: qkv = x @ w_attn + b, scatter epilogue ----------------
// 128x128 tile, BK=32, 4 waves, dbuf global_load_lds staging. Known-good (717 TF).
// NOTE: SQ_LDS_BANK_CONFLICT ~6.29M is STRUCTURAL b128 accounting (8 lanes/bank =
// floor for 1024B/wave reads) — R4 proved swizzles can't move it. 256²/8-phase port
// rejected for this shape: 384 tiles @1 block/CU = 1.5 blocks/CU -> 75% tail
// efficiency eats the 8-phase gain (636 < 717 TF effective).
template <int EPI>
__global__ __launch_bounds__(256) void k_gemm(const u16* __restrict__ A,
                                              const u16* __restrict__ Bt,
                                              const float* __restrict__ bias,
                                              float* __restrict__ outp,
                                              u16* __restrict__ q_out,
                                              u16* __restrict__ k_out,
                                              u16* __restrict__ vt_out,
                                              int K, int nIter) {
  __shared__ u16 As[2][4096];
  __shared__ u16 Bs[2][4096];
  int tid = threadIdx.x, w = tid >> 6, l = tid & 63;
  int r = l & 15, qd = l >> 4;
  int id = blockIdx.x;
  int xcd = id & 7, s0 = id >> 3;
  int mBlk = xcd * 8 + (s0 & 7);
  int nBlk = s0 >> 3;
  f32x4 acc[4][4] = {};

  const u16* ga[2]; const u16* gb[2]; int lgrp[2];
#pragma unroll
  for (int qq = 0; qq < 2; ++qq) {
    int grp = 2 * w + qq;
    int rowA = mBlk * 128 + grp * 16 + (l >> 2);
    int rowB = nBlk * 128 + grp * 16 + (l >> 2);
    int kcol = (l & 3) * 8;
    ga[qq] = A + (size_t)rowA * K + kcol;
    gb[qq] = Bt + (size_t)rowB * K + kcol;
    lgrp[qq] = grp * 512;
  }
  int aoff = ((w & 1) * 4) * 512 + r * 32 + qd * 8;
  int boff = ((w >> 1) * 4) * 512 + r * 32 + qd * 8;

  auto stageg = [&](int kt, int buf) {
#pragma unroll
    for (int qq = 0; qq < 2; ++qq) {
      gll16(ga[qq] + kt * 32, As[buf] + lgrp[qq]);
      gll16(gb[qq] + kt * 32, Bs[buf] + lgrp[qq]);
    }
  };

  stageg(0, 0);
  __syncthreads();  // buf0 visible

  for (int kt = 0; kt < nIter; ++kt) {
    int cur = kt & 1;
    if (kt + 1 < nIter) stageg(kt + 1, cur ^ 1);  // prefetch flies under compute
    s16x8 af[4], bf[4];
#pragma unroll
    for (int i = 0; i < 4; ++i) af[i] = *(const s16x8*)(As[cur] + aoff + i * 512);
#pragma unroll
    for (int j = 0; j < 4; ++j) bf[j] = *(const s16x8*)(Bs[cur] + boff + j * 512);
#pragma unroll
    for (int i = 0; i < 4; ++i)
#pragma unroll
      for (int j = 0; j < 4; ++j) acc[i][j] = mfma16(af[i], bf[j], acc[i][j]);
    __syncthreads();  // reads of cur done + prefetch into cur^1 landed
  }

  const float QSCALE = 0.125f * 1.44269504088896f;  // folded into q for exp2-domain attn
  int rowBase = mBlk * 128 + (w & 1) * 64;
  int colBase = nBlk * 128 + (w >> 1) * 64;
#pragma unroll
  for (int i = 0; i < 4; ++i) {
#pragma unroll
    for (int j = 0; j < 4; ++j) {
      int col = colBase + j * 16 + r;
      float bv = bias[col];
      float vv[4];
#pragma unroll
      for (int g = 0; g < 4; ++g) vv[g] = acc[i][j][g] + bv;
      int row0 = rowBase + i * 16 + qd * 4;  // rows row0..row0+3 (same 2048-block)
      if (EPI == 0) {
        int which = col >> 10;
        int rem = col & 1023;
        int hh = rem >> 6, dd = rem & 63;
        int bb = row0 >> 11, tt0 = row0 & 2047;
        if (which == 2) {
          u16x4 pk;
#pragma unroll
          for (int g = 0; g < 4; ++g) pk[g] = f2bf(vv[g]);
          *(u16x4*)(vt_out + (((size_t)(bb * 16 + hh)) * 64 + dd) * 2048 + tt0) = pk;
        } else {
          u16* base = (which == 0) ? q_out : k_out;
#pragma unroll
          for (int g = 0; g < 4; ++g) {
            float v = vv[g];
            if (which == 0) v *= QSCALE;
            base[(((size_t)(bb * 16 + hh)) * 2048 + tt0 + g) * 64 + dd] = f2bf(v);
          }
        }
      } else {
#pragma unroll
        for (int g = 0; g < 4; ++g)
          outp[(size_t)(row0 + g) * 1024 + col] = vv[g];
      }
    }
  }
}

// ---------------- GEMM1 (proj): out = y @ w_proj + b, fp32 out ----------------
// Tile 128x64, BK=32, 4 waves (2M x 2N). Grid 1024 blocks = 4/CU -> 16 waves/CU.
// LDS = (128+64)*32*2B*2buf = 24KB.
__global__ __launch_bounds__(256) void k_gemmP(const u16* __restrict__ A,
                                               const u16* __restrict__ Bt,
                                               const float* __restrict__ bias,
                                               float* __restrict__ outp) {
  __shared__ u16 As[2][128 * 32];
  __shared__ u16 Bs[2][64 * 32];
  const int K = 1024;
  int tid = threadIdx.x, w = tid >> 6, l = tid & 63;
  int r = l & 15, qd = l >> 4;
  int wm = w >> 1, wn = w & 1;
  int id = blockIdx.x;
  int xcd = id & 7, s0 = id >> 3;
  int mBlk = xcd * 8 + (s0 & 7);   // 0..63
  int nBlk = s0 >> 3;              // 0..15
  f32x4 acc[4][2] = {};

  int kcol = (tid & 3) * 8;
  const u16* ga = A + (size_t)(mBlk * 128 + (tid >> 2)) * K + kcol;
  const u16* gb = Bt + (size_t)(nBlk * 64 + (tid >> 2)) * K + kcol;
  int aoff = (wm * 64 + r) * 32 + qd * 8;
  int boff = (wn * 32 + r) * 32 + qd * 8;

  auto stageg = [&](int kt, int buf) {
    gll16(ga + kt * 32, (char*)As[buf] + w * 1024);
    gll16(ga + (size_t)64 * K + kt * 32, (char*)As[buf] + 4096 + w * 1024);
    gll16(gb + kt * 32, (char*)Bs[buf] + w * 1024);
  };

  stageg(0, 0);
  __syncthreads();

  for (int kt = 0; kt < 32; ++kt) {
    int cur = kt & 1;
    if (kt + 1 < 32) stageg(kt + 1, cur ^ 1);
    s16x8 af[4], bf[2];
#pragma unroll
    for (int i = 0; i < 4; ++i) af[i] = *(const s16x8*)(As[cur] + aoff + i * 512);
#pragma unroll
    for (int j = 0; j < 2; ++j) bf[j] = *(const s16x8*)(Bs[cur] + boff + j * 512);
#pragma unroll
    for (int i = 0; i < 4; ++i)
#pragma unroll
      for (int j = 0; j < 2; ++j) acc[i][j] = mfma16(af[i], bf[j], acc[i][j]);
    __syncthreads();
  }

  int rowBase = mBlk * 128 + wm * 64;
  int colBase = nBlk * 64 + wn * 32;
#pragma unroll
  for (int i = 0; i < 4; ++i) {
#pragma unroll
    for (int j = 0; j < 2; ++j) {
      int col = colBase + j * 16 + r;
      float bv = bias[col];
      int row0 = rowBase + i * 16 + qd * 4;
#pragma unroll
      for (int g = 0; g < 4; ++g)
        outp[(size_t)(row0 + g) * 1024 + col] = acc[i][j][g] + bv;
    }
  }
}

// ---------------- flash attention v15: cross-tile pipeline, 3-buffer ----------------
// v14 base (in-register P, quartet-spread bx, VALU row-sum) + v15: triple-buffered
// K/V (48KB -> 3 blocks/CU) with schedule per iter kt:
//   stage(kt+2,b2) -> QK(kt+1, Ks[b1]) || PV(kt, Vs[b0]) -> smax(kt+1) -> barrier
// QK(kt+1) and PV(kt) are independent MFMA streams in one barrier-free region; the
// per-tile serial chain (kf -> QK -> exp2 -> permlane -> PV) moves off the critical
// path. pa carries across the iteration boundary in VGPRs (launch_bounds(256,3)
// -> 170 VGPR budget, est peak ~155).
// WAR safety: stage into b2 = buffer whose reads completed before the PREVIOUS
// barrier; reads of Ks[b1]/Vs[b0] are of tiles staged >=1 barrier ago.
__global__ __launch_bounds__(256, 3) void k_attn(const u16* __restrict__ qg,
                                                 const u16* __restrict__ kg,
                                                 const u16* __restrict__ vtg,
                                                 u16* __restrict__ yg) {
  __shared__ u16 Ks[3][64 * 64];   // [buf][row][8chunk ^ (row&7)]
  __shared__ u16 Vs[3][64 * 64];   // [buf][d]  [8chunk ^ (d&7)]

  int id = blockIdx.x;
  int xcd = id & 7;                // == bh & 7 -> same-head blocks share an XCD
  int slot = id >> 3;              // 0..127
  int bx = 4 * (slot >> 5) + (slot & 3);       // 0..15, quartet-spread (v14)
  int bh = (((slot >> 2) & 7) << 3) | xcd;     // 8 heads per xcd
  int bb = bh >> 4, hh = bh & 15;
  int tid = threadIdx.x, w = tid >> 6, l = tid & 63;
  int r = l & 15, qd = l >> 4;

  const int chunk0 = bx, chunk1 = 31 - bx;
  int nmax = 32 - bx;              // chunk1 active every iter; chunk0 for kt <= bx
  int qloc = w * 16 + r;           // within-chunk q row owned by lane r

  // Q b-fragments (q pre-scaled by 1/8*log2e at GEMM0 epilogue)
  s16x8 qf[2][2];
#pragma unroll
  for (int c = 0; c < 2; ++c) {
    int qbase = (c ? chunk1 : chunk0) * 64 + w * 16;
#pragma unroll
    for (int s = 0; s < 2; ++s)
      qf[c][s] = *(const s16x8*)(qg + ((size_t)bh * 2048 + qbase + r) * 64 + s * 32 + qd * 8);
  }

  f32x4 o[2][4] = {};       // O^T: o[c][j][g] = O[q=qbase_c + r][d = 16j + 4qd + g]
  float lsum[2] = {0.f, 0.f};  // per-lane partial row-sum

  // staging lane geometry
  int rl = l >> 3;
  int cg = (l & 7) ^ rl;
  const u16* kbase = kg + (size_t)bh * 2048 * 64;
  const u16* vbase = vtg + (size_t)bh * 64 * 2048;

  auto stage = [&](int kt, int buf) {
    int kk0 = kt * 64;
#pragma unroll
    for (int p = 0; p < 2; ++p) {
      int row = p * 32 + w * 8 + rl;
      gll16(kbase + ((size_t)(kk0 + row)) * 64 + cg * 8, Ks[buf] + p * 2048 + w * 512);
      gll16(vbase + (size_t)row * 2048 + kk0 + cg * 8, Vs[buf] + p * 2048 + w * 512);
    }
  };

  // QK^T for one tile from Ks[buf]: fills sc1 (chunk1) and sc0 if act0
  auto qk = [&](int buf, f32x4 (&sc0)[4], f32x4 (&sc1)[4], bool act0) {
#pragma unroll
    for (int j = 0; j < 4; ++j) {
      sc1[j] = f32x4{0.f, 0.f, 0.f, 0.f};
      if (act0) sc0[j] = f32x4{0.f, 0.f, 0.f, 0.f};
    }
    __builtin_amdgcn_s_setprio(1);
#pragma unroll
    for (int s = 0; s < 2; ++s) {
#pragma unroll
      for (int j = 0; j < 4; ++j) {
        s16x8 kf = *(const s16x8*)(Ks[buf] + (16 * j + r) * 64 + ((s * 4 + qd) ^ (r & 7)) * 8);
        sc1[j] = mfma16(kf, qf[1][s], sc1[j]);
        if (act0) sc0[j] = mfma16(kf, qf[0][s], sc0[j]);
      }
    }
    __builtin_amdgcn_s_setprio(0);
  };

  // PV for one tile from Vs[buf] using held pa fragments
  auto pv = [&](int buf, s16x8 (&pa0)[2], s16x8 (&pa1)[2], bool act0) {
    __builtin_amdgcn_s_setprio(1);
#pragma unroll
    for (int s = 0; s < 2; ++s) {
#pragma unroll
      for (int j = 0; j < 4; ++j) {
        s16x8 vf = *(const s16x8*)(Vs[buf] + (16 * j + r) * 64 + ((s * 4 + qd) ^ (r & 7)) * 8);
        o[1][j] = mfma16(vf, pa1[s], o[1][j]);
        if (act0) o[0][j] = mfma16(vf, pa0[s], o[0][j]);
      }
    }
    __builtin_amdgcn_s_setprio(0);
  };

  // softmax: S^T fragments -> PV B-operand fragments, in-register (permlane swaps)
  auto smax = [&](f32x4 (&sc)[4], s16x8 (&pac)[2], bool mask, float& sum) {
    unsigned pk[4][2];
#pragma unroll
    for (int j = 0; j < 4; ++j) {
      float p0, p1, p2, p3;  // k-local = 16j + 4qd + g
      if (mask) {
        int kb0 = 16 * j + 4 * qd;
        p0 = (kb0 + 0 > qloc) ? 0.f : __builtin_amdgcn_exp2f(sc[j][0]);
        p1 = (kb0 + 1 > qloc) ? 0.f : __builtin_amdgcn_exp2f(sc[j][1]);
        p2 = (kb0 + 2 > qloc) ? 0.f : __builtin_amdgcn_exp2f(sc[j][2]);
        p3 = (kb0 + 3 > qloc) ? 0.f : __builtin_amdgcn_exp2f(sc[j][3]);
      } else {
        p0 = __builtin_amdgcn_exp2f(sc[j][0]);
        p1 = __builtin_amdgcn_exp2f(sc[j][1]);
        p2 = __builtin_amdgcn_exp2f(sc[j][2]);
        p3 = __builtin_amdgcn_exp2f(sc[j][3]);
      }
      sum += (p0 + p1) + (p2 + p3);   // VALU row-sum partial
      pk[j][0] = pk_trunc(p1, p0);
      pk[j][1] = pk_trunc(p3, p2);
    }
#pragma unroll
    for (int s = 0; s < 2; ++s) {
      unsigned a0 = pk[2 * s][0], b0 = pk[2 * s + 1][0];
      asm("v_permlane32_swap_b32 %0, %1" : "+v"(a0), "+v"(b0));
      asm("v_permlane16_swap_b32 %0, %1" : "+v"(a0), "+v"(b0));
      unsigned a1 = pk[2 * s][1], b1 = pk[2 * s + 1][1];
      asm("v_permlane32_swap_b32 %0, %1" : "+v"(a1), "+v"(b1));
      asm("v_permlane16_swap_b32 %0, %1" : "+v"(a1), "+v"(b1));
      pac[s] = mk_pa(a0, a1, b0, b1);
    }
  };

  // prologue: stage tiles 0,1; prime pipeline with QK(0)+smax(0)
  stage(0, 0);
  stage(1, 1);
  __syncthreads();  // tiles 0,1 visible

  f32x4 cs0[4], cs1[4];
  qk(0, cs0, cs1, true);            // kt=0: chunk0 always active (0 <= bx)
  s16x8 pa0c[2], pa1c[2];
  smax(cs1, pa1c, 0 == chunk1, lsum[1]);
  smax(cs0, pa0c, 0 == chunk0, lsum[0]);

  int b0 = 0, b1 = 1, b2 = 2;
  for (int kt = 0; kt < nmax; ++kt) {
    if (kt + 2 < nmax) stage(kt + 2, b2);   // lands before next barrier
    bool act0c = (kt <= bx);
    bool haven = (kt + 1 < nmax);
    bool act0n = (kt + 1 <= bx);

    // two independent MFMA streams: QK(kt+1) from Ks[b1], PV(kt) from Vs[b0]
    f32x4 ns0[4], ns1[4];
    if (haven) qk(b1, ns0, ns1, act0n);
    pv(b0, pa0c, pa1c, act0c);

    // softmax(kt+1): trans/VALU work drains under the MFMA tail
    s16x8 pa0n[2], pa1n[2];
    if (haven) {
      smax(ns1, pa1n, (kt + 1) == chunk1, lsum[1]);
      if (act0n) smax(ns0, pa0n, (kt + 1) == chunk0, lsum[0]);
    }

    __syncthreads();  // publishes tile kt+2; all reads of b0/b1 this iter done
    int t = b0; b0 = b1; b1 = b2; b2 = t;
    if (haven) {
      pa1c[0] = pa1n[0]; pa1c[1] = pa1n[1];
      if (act0n) { pa0c[0] = pa0n[0]; pa0c[1] = pa0n[1]; }
    }
  }

  // epilogue: reduce row-sum across the 4 qd-lanes (r, r+16, r+32, r+48), then store
#pragma unroll
  for (int c = 0; c < 2; ++c) {
    int qbase = (c ? chunk1 : chunk0) * 64 + w * 16;
    float tot = lsum[c];
    tot += __shfl_xor(tot, 16);
    tot += __shfl_xor(tot, 32);
    float inv = 1.0f / tot;
    size_t rowoff = ((size_t)bb * 2048 + qbase + r) * 1024 + hh * 64;
#pragma unroll
    for (int j = 0; j < 4; ++j) {
      u16x4 yv;
      yv[0] = f2bf(o[c][j][0] * inv);
      yv[1] = f2bf(o[c][j][1] * inv);
      yv[2] = f2bf(o[c][j][2] * inv);
      yv[3] = f2bf(o[c][j][3] * inv);
      *(u16x4*)(yg + rowoff + 16 * j + 4 * qd) = yv;
    }
  }
}

// ---------------- launch ----------------
extern "C" void kernel_launch(void* const* d_in, const int* in_sizes, int n_in,
                              void* d_out, int out_size, void* d_ws, size_t ws_size,
                              hipStream_t stream) {
  const float* x      = (const float*)d_in[0];
  const float* w_attn = (const float*)d_in[1];
  const float* b_attn = (const float*)d_in[2];
  const float* w_proj = (const float*)d_in[3];
  const float* b_proj = (const float*)d_in[4];
  float* out = (float*)d_out;

  char* ws = (char*)d_ws;
  size_t off = 0;
  auto alloc = [&](size_t bytes) -> void* {
    void* p = ws + off;
    off += (bytes + 255) & ~(size_t)255;
    return p;
  };
  const size_t BT = 8192, C = 1024;
  u16* xb  = (u16*)alloc(BT * C * 2);          // x bf16; reused as y
  u16* waT = (u16*)alloc(3072 * 1024 * 2);
  u16* wpT = (u16*)alloc(1024 * 1024 * 2);
  u16* qb  = (u16*)alloc(BT * C * 2);          // [BH][T][D], q pre-scaled
  u16* kb  = (u16*)alloc(BT * C * 2);          // [BH][T][D]
  u16* vtb = (u16*)alloc(BT * C * 2);          // [BH][D][T] (written by GEMM0 directly)
  (void)ws_size; (void)in_sizes; (void)n_in; (void)out_size;

  k_prep<<<4096 + 3072 + 1024, 256, 0, stream>>>(x, xb, w_attn, waT, w_proj, wpT);
  k_gemm<0><<<1536, 256, 0, stream>>>(xb, waT, b_attn, nullptr, qb, kb, vtb, 1024, 32);
  k_attn<<<1024, 256, 0, stream>>>(qb, kb, vtb, xb /* y reuses xb */);
  k_gemmP<<<1024, 256, 0, stream>>>(xb, wpT, b_proj, out);
}

// Round 13
// 235.657 us; speedup vs baseline: 1.0752x; 1.0752x over previous
//
#include <hip/hip_runtime.h>
#include <math.h>

// ---------------- types / helpers ----------------
typedef short s16x8 __attribute__((ext_vector_type(8)));     // 8 bf16 in 4 VGPRs
typedef unsigned short u16;
typedef unsigned short u16x4 __attribute__((ext_vector_type(4)));
typedef float f32x4 __attribute__((ext_vector_type(4)));

__device__ __forceinline__ f32x4 mfma16(s16x8 a, s16x8 b, f32x4 c) {
  return __builtin_amdgcn_mfma_f32_16x16x32_bf16(a, b, c, 0, 0, 0);
}

// fp32 -> bf16 bits, round-to-nearest-even
__device__ __forceinline__ u16 f2bf(float f) {
  unsigned u = __builtin_bit_cast(unsigned, f);
  u = (u + 0x7fffu + ((u >> 16) & 1u)) >> 16;
  return (u16)u;
}

// pack two fp32 -> two truncated bf16 in one v_perm
__device__ __forceinline__ unsigned pk_trunc(float hi, float lo) {
  return __builtin_amdgcn_perm(__builtin_bit_cast(unsigned, hi),
                               __builtin_bit_cast(unsigned, lo), 0x07060302u);
}

__device__ __forceinline__ s16x8 mk_pa(unsigned a, unsigned b, unsigned c, unsigned d) {
  union { unsigned u[4]; s16x8 h; } t;
  t.u[0] = a; t.u[1] = b; t.u[2] = c; t.u[3] = d;
  return t.h;
}

// async global->LDS, 16B per lane; lds base wave-uniform, lane i lands at base + i*16
__device__ __forceinline__ void gll16(const void* g, void* l) {
  __builtin_amdgcn_global_load_lds((__attribute__((address_space(1))) void*)(void*)g,
                                   (__attribute__((address_space(3))) void*)l,
                                   16, 0, 0);
}

// ---------------- fused prep: x->bf16 convert + both weight transposes ----------------
// R9 LESSON: do NOT fuse the x-convert into gemm0 via fp32 LDS staging. fp32 A-tile
// row stride = 128B makes the fragment-read bank index independent of r -> 16-way
// conflict (SQ_LDS_BANK_CONFLICT 6.29M -> 22.0M, gemm0 72 -> 110.6 us). The bf16
// 64B-stride layout is at the balanced 8-accesses/bank floor. Convert stays here.
__device__ __forceinline__ void transpose_body(const float* __restrict__ in,
                                               u16* __restrict__ out, int R, int C,
                                               int bx, int by, float (*tile)[33]) {
  int c0 = bx * 32, r0 = by * 32;
  int tx = threadIdx.x & 31, ty = threadIdx.x >> 5;  // 32 x 8
#pragma unroll
  for (int s = 0; s < 4; ++s)
    tile[ty + 8 * s][tx] = in[(size_t)(r0 + ty + 8 * s) * C + c0 + tx];
  __syncthreads();
#pragma unroll
  for (int s = 0; s < 4; ++s)
    out[(size_t)(c0 + ty + 8 * s) * R + r0 + tx] = f2bf(tile[tx][ty + 8 * s]);
}

__global__ __launch_bounds__(256) void k_prep(const float* __restrict__ x,
                                              u16* __restrict__ xb,
                                              const float* __restrict__ w_attn,
                                              u16* __restrict__ waT,
                                              const float* __restrict__ w_proj,
                                              u16* __restrict__ wpT) {
  __shared__ float tile[32][33];
  int id = blockIdx.x;
  if (id < 4096) {
    int i = (id * 256 + threadIdx.x) * 8;
    const float4* xv = (const float4*)(x + i);
    float4 a = xv[0], b = xv[1];
    union { s16x8 v; u16 s[8]; } r;
    r.s[0] = f2bf(a.x); r.s[1] = f2bf(a.y); r.s[2] = f2bf(a.z); r.s[3] = f2bf(a.w);
    r.s[4] = f2bf(b.x); r.s[5] = f2bf(b.y); r.s[6] = f2bf(b.z); r.s[7] = f2bf(b.w);
    *(s16x8*)(xb + i) = r.v;
  } else if (id < 4096 + 3072) {
    int t = id - 4096;                      // w_attn [1024][3072] -> [3072][1024]
    transpose_body(w_attn, waT, 1024, 3072, t % 96, t / 96, tile);
  } else {
    int t = id - (4096 + 3072);             // w_proj [1024][1024] -> [1024][1024]^T
    transpose_body(w_proj, wpT, 1024, 1024, t % 32, t / 32, tile);
  }
}

// ---------------- GEMM0: qkv = x @ w_attn + b, scatter epilogue ----------------
// 128x128 tile, BK=32, 4 waves, dbuf global_load_lds staging. Known-good (717 TF).
// NOTE: SQ_LDS_BANK_CONFLICT ~6.29M is STRUCTURAL b128 accounting (8 lanes/bank =
// floor for 1024B/wave reads) — R4 proved swizzles can't move it. 256²/8-phase port
// rejected for this shape: 384 tiles @1 block/CU = 1.5 blocks/CU -> 75% tail
// efficiency eats the 8-phase gain (636 < 717 TF effective).
template <int EPI>
__global__ __launch_bounds__(256) void k_gemm(const u16* __restrict__ A,
                                              const u16* __restrict__ Bt,
                                              const float* __restrict__ bias,
                                              float* __restrict__ outp,
                                              u16* __restrict__ q_out,
                                              u16* __restrict__ k_out,
                                              u16* __restrict__ vt_out,
                                              int K, int nIter) {
  __shared__ u16 As[2][4096];
  __shared__ u16 Bs[2][4096];
  int tid = threadIdx.x, w = tid >> 6, l = tid & 63;
  int r = l & 15, qd = l >> 4;
  int id = blockIdx.x;
  int xcd = id & 7, s0 = id >> 3;
  int mBlk = xcd * 8 + (s0 & 7);
  int nBlk = s0 >> 3;
  f32x4 acc[4][4] = {};

  const u16* ga[2]; const u16* gb[2]; int lgrp[2];
#pragma unroll
  for (int qq = 0; qq < 2; ++qq) {
    int grp = 2 * w + qq;
    int rowA = mBlk * 128 + grp * 16 + (l >> 2);
    int rowB = nBlk * 128 + grp * 16 + (l >> 2);
    int kcol = (l & 3) * 8;
    ga[qq] = A + (size_t)rowA * K + kcol;
    gb[qq] = Bt + (size_t)rowB * K + kcol;
    lgrp[qq] = grp * 512;
  }
  int aoff = ((w & 1) * 4) * 512 + r * 32 + qd * 8;
  int boff = ((w >> 1) * 4) * 512 + r * 32 + qd * 8;

  auto stageg = [&](int kt, int buf) {
#pragma unroll
    for (int qq = 0; qq < 2; ++qq) {
      gll16(ga[qq] + kt * 32, As[buf] + lgrp[qq]);
      gll16(gb[qq] + kt * 32, Bs[buf] + lgrp[qq]);
    }
  };

  stageg(0, 0);
  __syncthreads();  // buf0 visible

  for (int kt = 0; kt < nIter; ++kt) {
    int cur = kt & 1;
    if (kt + 1 < nIter) stageg(kt + 1, cur ^ 1);  // prefetch flies under compute
    s16x8 af[4], bf[4];
#pragma unroll
    for (int i = 0; i < 4; ++i) af[i] = *(const s16x8*)(As[cur] + aoff + i * 512);
#pragma unroll
    for (int j = 0; j < 4; ++j) bf[j] = *(const s16x8*)(Bs[cur] + boff + j * 512);
#pragma unroll
    for (int i = 0; i < 4; ++i)
#pragma unroll
      for (int j = 0; j < 4; ++j) acc[i][j] = mfma16(af[i], bf[j], acc[i][j]);
    __syncthreads();  // reads of cur done + prefetch into cur^1 landed
  }

  const float QSCALE = 0.125f * 1.44269504088896f;  // folded into q for exp2-domain attn
  int rowBase = mBlk * 128 + (w & 1) * 64;
  int colBase = nBlk * 128 + (w >> 1) * 64;
#pragma unroll
  for (int i = 0; i < 4; ++i) {
#pragma unroll
    for (int j = 0; j < 4; ++j) {
      int col = colBase + j * 16 + r;
      float bv = bias[col];
      float vv[4];
#pragma unroll
      for (int g = 0; g < 4; ++g) vv[g] = acc[i][j][g] + bv;
      int row0 = rowBase + i * 16 + qd * 4;  // rows row0..row0+3 (same 2048-block)
      if (EPI == 0) {
        int which = col >> 10;
        int rem = col & 1023;
        int hh = rem >> 6, dd = rem & 63;
        int bb = row0 >> 11, tt0 = row0 & 2047;
        if (which == 2) {
          u16x4 pk;
#pragma unroll
          for (int g = 0; g < 4; ++g) pk[g] = f2bf(vv[g]);
          *(u16x4*)(vt_out + (((size_t)(bb * 16 + hh)) * 64 + dd) * 2048 + tt0) = pk;
        } else {
          u16* base = (which == 0) ? q_out : k_out;
#pragma unroll
          for (int g = 0; g < 4; ++g) {
            float v = vv[g];
            if (which == 0) v *= QSCALE;
            base[(((size_t)(bb * 16 + hh)) * 2048 + tt0 + g) * 64 + dd] = f2bf(v);
          }
        }
      } else {
#pragma unroll
        for (int g = 0; g < 4; ++g)
          outp[(size_t)(row0 + g) * 1024 + col] = vv[g];
      }
    }
  }
}

// ---------------- GEMM1 (proj): out = y @ w_proj + b, fp32 out ----------------
// Tile 128x64, BK=32, 4 waves (2M x 2N). Grid 1024 blocks = 4/CU -> 16 waves/CU.
// LDS = (128+64)*32*2B*2buf = 24KB.
__global__ __launch_bounds__(256) void k_gemmP(const u16* __restrict__ A,
                                               const u16* __restrict__ Bt,
                                               const float* __restrict__ bias,
                                               float* __restrict__ outp) {
  __shared__ u16 As[2][128 * 32];
  __shared__ u16 Bs[2][64 * 32];
  const int K = 1024;
  int tid = threadIdx.x, w = tid >> 6, l = tid & 63;
  int r = l & 15, qd = l >> 4;
  int wm = w >> 1, wn = w & 1;
  int id = blockIdx.x;
  int xcd = id & 7, s0 = id >> 3;
  int mBlk = xcd * 8 + (s0 & 7);   // 0..63
  int nBlk = s0 >> 3;              // 0..15
  f32x4 acc[4][2] = {};

  int kcol = (tid & 3) * 8;
  const u16* ga = A + (size_t)(mBlk * 128 + (tid >> 2)) * K + kcol;
  const u16* gb = Bt + (size_t)(nBlk * 64 + (tid >> 2)) * K + kcol;
  int aoff = (wm * 64 + r) * 32 + qd * 8;
  int boff = (wn * 32 + r) * 32 + qd * 8;

  auto stageg = [&](int kt, int buf) {
    gll16(ga + kt * 32, (char*)As[buf] + w * 1024);
    gll16(ga + (size_t)64 * K + kt * 32, (char*)As[buf] + 4096 + w * 1024);
    gll16(gb + kt * 32, (char*)Bs[buf] + w * 1024);
  };

  stageg(0, 0);
  __syncthreads();

  for (int kt = 0; kt < 32; ++kt) {
    int cur = kt & 1;
    if (kt + 1 < 32) stageg(kt + 1, cur ^ 1);
    s16x8 af[4], bf[2];
#pragma unroll
    for (int i = 0; i < 4; ++i) af[i] = *(const s16x8*)(As[cur] + aoff + i * 512);
#pragma unroll
    for (int j = 0; j < 2; ++j) bf[j] = *(const s16x8*)(Bs[cur] + boff + j * 512);
#pragma unroll
    for (int i = 0; i < 4; ++i)
#pragma unroll
      for (int j = 0; j < 2; ++j) acc[i][j] = mfma16(af[i], bf[j], acc[i][j]);
    __syncthreads();
  }

  int rowBase = mBlk * 128 + wm * 64;
  int colBase = nBlk * 64 + wn * 32;
#pragma unroll
  for (int i = 0; i < 4; ++i) {
#pragma unroll
    for (int j = 0; j < 2; ++j) {
      int col = colBase + j * 16 + r;
      float bv = bias[col];
      int row0 = rowBase + i * 16 + qd * 4;
#pragma unroll
      for (int g = 0; g < 4; ++g)
        outp[(size_t)(row0 + g) * 1024 + col] = acc[i][j][g] + bv;
    }
  }
}

// ---------------- flash attention (v14: quartet-spread bx) ----------------
// In-register P via permlane, 4 blocks/CU, VALU row-sum, dbuf K/V.
// v14: bx = 4*(slot>>5) + (slot&3) spreads each same-CU quartet across loop
// lengths {b0, b0+4, b0+8, b0+12} -> per-CU iteration totals 92..104.
// R12 LESSON (v15 refuted): cross-tile pipelining (QK(kt+1) || PV(kt), 3-buffer,
// 3 blocks/CU) REGRESSED attn 
//   ~65 -> 77 us: smax moved onto the critical path (VALUBusy 38%) and the
//   25% occupancy loss cost more than the chain overlap bought. With R1's
//   neutral counted-vmcnt attempt, the chain theory is refuted from both sides:
//   at this tile size, 4 blocks/CU of TLP is the structure's operating point.
__global__ __launch_bounds__(256, 4) void k_attn(const u16* __restrict__ qg,
                                                 const u16* __restrict__ kg,
                                                 const u16* __restrict__ vtg,
                                                 u16* __restrict__ yg) {
  __shared__ u16 Ks[2][64 * 64];   // [buf][row][8chunk ^ (row&7)]
  __shared__ u16 Vs[2][64 * 64];   // [buf][d]  [8chunk ^ (d&7)]

  int id = blockIdx.x;
  int xcd = id & 7;                // == bh & 7 -> same-head blocks share an XCD
  int slot = id >> 3;              // 0..127
  int bx = 4 * (slot >> 5) + (slot & 3);       // 0..15, quartet-spread
  int bh = (((slot >> 2) & 7) << 3) | xcd;     // 8 heads per xcd
  int bb = bh >> 4, hh = bh & 15;
  int tid = threadIdx.x, w = tid >> 6, l = tid & 63;
  int r = l & 15, qd = l >> 4;

  const int chunk0 = bx, chunk1 = 31 - bx;
  int nmax = 32 - bx;              // chunk1 active every iter; chunk0 for kt <= bx
  int qloc = w * 16 + r;           // within-chunk q row owned by lane r

  // Q b-fragments (q pre-scaled by 1/8*log2e at GEMM0 epilogue)
  s16x8 qf[2][2];
#pragma unroll
  for (int c = 0; c < 2; ++c) {
    int qbase = (c ? chunk1 : chunk0) * 64 + w * 16;
#pragma unroll
    for (int s = 0; s < 2; ++s)
      qf[c][s] = *(const s16x8*)(qg + ((size_t)bh * 2048 + qbase + r) * 64 + s * 32 + qd * 8);
  }

  f32x4 o[2][4] = {};       // O^T: o[c][j][g] = O[q=qbase_c + r][d = 16j + 4qd + g]
  float lsum[2] = {0.f, 0.f};  // per-lane partial row-sum (16 of 64 k's per lane)

  // staging lane geometry
  int rl = l >> 3;
  int cg = (l & 7) ^ rl;
  const u16* kbase = kg + (size_t)bh * 2048 * 64;
  const u16* vbase = vtg + (size_t)bh * 64 * 2048;

  auto stage = [&](int kt, int buf) {
    int kk0 = kt * 64;
#pragma unroll
    for (int p = 0; p < 2; ++p) {
      int row = p * 32 + w * 8 + rl;
      gll16(kbase + ((size_t)(kk0 + row)) * 64 + cg * 8, Ks[buf] + p * 2048 + w * 512);
      gll16(vbase + (size_t)row * 2048 + kk0 + cg * 8, Vs[buf] + p * 2048 + w * 512);
    }
  };

  // softmax: S^T fragments -> PV B-operand fragments, in-register (permlane swaps)
  auto smax = [&](f32x4 (&sc)[4], s16x8 (&pac)[2], bool mask, float& sum) {
    unsigned pk[4][2];
#pragma unroll
    for (int j = 0; j < 4; ++j) {
      float p0, p1, p2, p3;  // k-local = 16j + 4qd + g
      if (mask) {
        int kb0 = 16 * j + 4 * qd;
        p0 = (kb0 + 0 > qloc) ? 0.f : __builtin_amdgcn_exp2f(sc[j][0]);
        p1 = (kb0 + 1 > qloc) ? 0.f : __builtin_amdgcn_exp2f(sc[j][1]);
        p2 = (kb0 + 2 > qloc) ? 0.f : __builtin_amdgcn_exp2f(sc[j][2]);
        p3 = (kb0 + 3 > qloc) ? 0.f : __builtin_amdgcn_exp2f(sc[j][3]);
      } else {
        p0 = __builtin_amdgcn_exp2f(sc[j][0]);
        p1 = __builtin_amdgcn_exp2f(sc[j][1]);
        p2 = __builtin_amdgcn_exp2f(sc[j][2]);
        p3 = __builtin_amdgcn_exp2f(sc[j][3]);
      }
      sum += (p0 + p1) + (p2 + p3);   // VALU row-sum partial
      pk[j][0] = pk_trunc(p1, p0);
      pk[j][1] = pk_trunc(p3, p2);
    }
#pragma unroll
    for (int s = 0; s < 2; ++s) {
      unsigned a0 = pk[2 * s][0], b0 = pk[2 * s + 1][0];
      asm("v_permlane32_swap_b32 %0, %1" : "+v"(a0), "+v"(b0));
      asm("v_permlane16_swap_b32 %0, %1" : "+v"(a0), "+v"(b0));
      unsigned a1 = pk[2 * s][1], b1 = pk[2 * s + 1][1];
      asm("v_permlane32_swap_b32 %0, %1" : "+v"(a1), "+v"(b1));
      asm("v_permlane16_swap_b32 %0, %1" : "+v"(a1), "+v"(b1));
      pac[s] = mk_pa(a0, a1, b0, b1);
    }
  };

  stage(0, 0);
  __syncthreads();  // buf0 visible

  for (int kt = 0; kt < nmax; ++kt) {
    int cur = kt & 1;
    if (kt + 1 < nmax) stage(kt + 1, cur ^ 1);  // prefetch flies under compute
    bool act0 = (kt <= bx);

    // ---- QK^T: kf read once, feeds both chunks ----
    f32x4 s0[4], s1[4];
#pragma unroll
    for (int j = 0; j < 4; ++j) {
      s1[j] = f32x4{0.f, 0.f, 0.f, 0.f};
      if (act0) s0[j] = f32x4{0.f, 0.f, 0.f, 0.f};
    }
    __builtin_amdgcn_s_setprio(1);
#pragma unroll
    for (int s = 0; s < 2; ++s) {
#pragma unroll
      for (int j = 0; j < 4; ++j) {
        s16x8 kf = *(const s16x8*)(Ks[cur] + (16 * j + r) * 64 + ((s * 4 + qd) ^ (r & 7)) * 8);
        s1[j] = mfma16(kf, qf[1][s], s1[j]);
        if (act0) s0[j] = mfma16(kf, qf[0][s], s0[j]);
      }
    }
    __builtin_amdgcn_s_setprio(0);

    // ---- softmax + in-register P redistribution ----
    s16x8 pa0[2], pa1[2];
    smax(s1, pa1, kt == chunk1, lsum[1]);
    if (act0) smax(s0, pa0, kt == chunk0, lsum[0]);

    // ---- PV: vf read once, feeds both chunks ----
    __builtin_amdgcn_s_setprio(1);
#pragma unroll
    for (int s = 0; s < 2; ++s) {
#pragma unroll
      for (int j = 0; j < 4; ++j) {
        s16x8 vf = *(const s16x8*)(Vs[cur] + (16 * j + r) * 64 + ((s * 4 + qd) ^ (r & 7)) * 8);
        o[1][j] = mfma16(vf, pa1[s], o[1][j]);
        if (act0) o[0][j] = mfma16(vf, pa0[s], o[0][j]);
      }
    }
    __builtin_amdgcn_s_setprio(0);

    __syncthreads();  // reads of buf[cur] done + prefetch into buf[cur^1] landed
  }

  // epilogue: reduce row-sum across the 4 qd-lanes (r, r+16, r+32, r+48), then store
#pragma unroll
  for (int c = 0; c < 2; ++c) {
    int qbase = (c ? chunk1 : chunk0) * 64 + w * 16;
    float tot = lsum[c];
    tot += __shfl_xor(tot, 16);
    tot += __shfl_xor(tot, 32);
    float inv = 1.0f / tot;
    size_t rowoff = ((size_t)bb * 2048 + qbase + r) * 1024 + hh * 64;
#pragma unroll
    for (int j = 0; j < 4; ++j) {
      u16x4 yv;
      yv[0] = f2bf(o[c][j][0] * inv);
      yv[1] = f2bf(o[c][j][1] * inv);
      yv[2] = f2bf(o[c][j][2] * inv);
      yv[3] = f2bf(o[c][j][3] * inv);
      *(u16x4*)(yg + rowoff + 16 * j + 4 * qd) = yv;
    }
  }
}

// ---------------- launch ----------------
extern "C" void kernel_launch(void* const* d_in, const int* in_sizes, int n_in,
                              void* d_out, int out_size, void* d_ws, size_t ws_size,
                              hipStream_t stream) {
  const float* x      = (const float*)d_in[0];
  const float* w_attn = (const float*)d_in[1];
  const float* b_attn = (const float*)d_in[2];
  const float* w_proj = (const float*)d_in[3];
  const float* b_proj = (const float*)d_in[4];
  float* out = (float*)d_out;

  char* ws = (char*)d_ws;
  size_t off = 0;
  auto alloc = [&](size_t bytes) -> void* {
    void* p = ws + off;
    off += (bytes + 255) & ~(size_t)255;
    return p;
  };
  const size_t BT = 8192, C = 1024;
  u16* xb  = (u16*)alloc(BT * C * 2);          // x bf16; reused as y
  u16* waT = (u16*)alloc(3072 * 1024 * 2);
  u16* wpT = (u16*)alloc(1024 * 1024 * 2);
  u16* qb  = (u16*)alloc(BT * C * 2);          // [BH][T][D], q pre-scaled
  u16* kb  = (u16*)alloc(BT * C * 2);          // [BH][T][D]
  u16* vtb = (u16*)alloc(BT * C * 2);          // [BH][D][T] (written by GEMM0 directly)
  (void)ws_size; (void)in_sizes; (void)n_in; (void)out_size;

  k_prep<<<4096 + 3072 + 1024, 256, 0, stream>>>(x, xb, w_attn, waT, w_proj, wpT);
  k_gemm<0><<<1536, 256, 0, stream>>>(xb, waT, b_attn, nullptr, qb, kb, vtb, 1024, 32);
  k_attn<<<1024, 256, 0, stream>>>(qb, kb, vtb, xb /* y reuses xb */);
  k_gemmP<<<1024, 256, 0, stream>>>(xb, wpT, b_proj, out);
}